// Round 1
// baseline (415.202 us; speedup 1.0000x reference)
//
#include <hip/hip_runtime.h>

// Box3dAttention: B=2, LQ=4096, d=256, heads=8, head_dim=32, 1 level, 5x5=25 points,
// feature map 188x188 (LV=35344). All fp32.
//
// ws layout (floats):
//   v         : M1*256          (value @ W_value^T + b, M1 = B*LV = 70688)  72.4 MB
//   out_heads : MQ*256          (MQ = B*LQ = 8192)                           8.4 MB
//   wts       : MQ*200 float4   (attn * bilinear * validity, per sample)    26.2 MB
//   lins      : MQ*200 int4     (clamped gather indices)                    26.2 MB
// total ~133 MB.

__global__ __launch_bounds__(256) void gemm_nt_bias(
    const float* __restrict__ A,    // M x 256 row-major
    const float* __restrict__ W,    // 256 x 256 row-major; computes A @ W^T
    const float* __restrict__ bias, // 256
    float* __restrict__ C,          // M x 256
    int M)
{
    const int K = 256, N = 256;
    __shared__ float As[16][68];
    __shared__ float Bs[16][68];
    int tid = threadIdx.x;
    int tcol = tid & 15, trow = tid >> 4;
    int m0 = blockIdx.x * 64, n0 = blockIdx.y * 64;
    int lr = tid >> 2;          // 0..63
    int lc = (tid & 3) << 2;    // 0,4,8,12
    float acc[4][4] = {};
    for (int k0 = 0; k0 < K; k0 += 16) {
        int arow = m0 + lr; if (arow > M - 1) arow = M - 1;
        float4 av = *(const float4*)(A + (size_t)arow * K + k0 + lc);
        float4 wv = *(const float4*)(W + (size_t)(n0 + lr) * K + k0 + lc);
        __syncthreads();
        As[lc + 0][lr] = av.x; As[lc + 1][lr] = av.y; As[lc + 2][lr] = av.z; As[lc + 3][lr] = av.w;
        Bs[lc + 0][lr] = wv.x; Bs[lc + 1][lr] = wv.y; Bs[lc + 2][lr] = wv.z; Bs[lc + 3][lr] = wv.w;
        __syncthreads();
#pragma unroll
        for (int k = 0; k < 16; ++k) {
            float4 a4 = *(const float4*)&As[k][trow << 2];
            float4 b4 = *(const float4*)&Bs[k][tcol << 2];
            float a[4] = {a4.x, a4.y, a4.z, a4.w};
            float bb[4] = {b4.x, b4.y, b4.z, b4.w};
#pragma unroll
            for (int i = 0; i < 4; i++)
#pragma unroll
                for (int j = 0; j < 4; j++) acc[i][j] += a[i] * bb[j];
        }
    }
#pragma unroll
    for (int i = 0; i < 4; i++) {
        int m = m0 + trow * 4 + i;
        if (m >= M) continue;
#pragma unroll
        for (int j = 0; j < 4; j++) {
            int n = n0 + tcol * 4 + j;
            C[(size_t)m * N + n] = acc[i][j] + bias[n];
        }
    }
}

// One block = 16 queries. Computes attn logits (200) + box offsets (40),
// softmax per head over 25 points (written to d_out attn region), then decodes
// boxes -> per-sample gather indices + combined weights into ws.
__global__ __launch_bounds__(256) void attn_box_kernel(
    const float* __restrict__ query,        // MQ x 256
    const float* __restrict__ ref_windows,  // MQ x 7
    const float* __restrict__ W_attn, const float* __restrict__ b_attn, // 200x256, 200
    const float* __restrict__ W_box,  const float* __restrict__ b_box,  // 40x256, 40
    float* __restrict__ attn_out,           // MQ*200 (second output)
    float4* __restrict__ wts,               // MQ*200
    int4* __restrict__ lins,                // MQ*200
    const int* __restrict__ Hf_p, const int* __restrict__ Wf_p)
{
    __shared__ float q_lds[16][256];
    __shared__ float logit[16][240];
    __shared__ float rw_lds[16][8];
    int tid = threadIdx.x;
    int m0 = blockIdx.x * 16;
#pragma unroll
    for (int r = 0; r < 16; ++r)
        q_lds[r][tid] = query[(size_t)(m0 + r) * 256 + tid];
    if (tid < 112) rw_lds[tid / 7][tid % 7] = ref_windows[(size_t)m0 * 7 + tid];
    __syncthreads();
    if (tid < 240) {
        const float* Wrow; float bz;
        if (tid < 200) { Wrow = W_attn + (size_t)tid * 256; bz = b_attn[tid]; }
        else           { Wrow = W_box + (size_t)(tid - 200) * 256; bz = b_box[tid - 200]; }
        float acc[16];
#pragma unroll
        for (int qi = 0; qi < 16; qi++) acc[qi] = bz;
        for (int k = 0; k < 256; k += 4) {
            float4 w = *(const float4*)(Wrow + k);
#pragma unroll
            for (int qi = 0; qi < 16; qi++) {
                float4 qv = *(const float4*)&q_lds[qi][k];
                acc[qi] += w.x * qv.x + w.y * qv.y + w.z * qv.z + w.w * qv.w;
            }
        }
#pragma unroll
        for (int qi = 0; qi < 16; qi++) logit[qi][tid] = acc[qi];
    }
    __syncthreads();
    if (tid < 128) {
        int qi = tid >> 3, h = tid & 7;
        size_t m = (size_t)m0 + qi;
        float e[25];
        float mx = -1e30f;
#pragma unroll
        for (int p = 0; p < 25; p++) mx = fmaxf(mx, logit[qi][h * 25 + p]);
        float s = 0.f;
#pragma unroll
        for (int p = 0; p < 25; p++) { e[p] = expf(logit[qi][h * 25 + p] - mx); s += e[p]; }
        float inv = 1.f / s;
        size_t base = (m * 8 + h) * 25;
#pragma unroll
        for (int p = 0; p < 25; p++) { e[p] *= inv; attn_out[base + p] = e[p]; }

        int Hf = *Hf_p, Wf = *Wf_p;
        float rw0 = rw_lds[qi][0], rw1 = rw_lds[qi][1], rw3 = rw_lds[qi][3],
              rw4 = rw_lds[qi][4], rw6 = rw_lds[qi][6];
        float ob0 = logit[qi][200 + h * 5 + 0];
        float ob1 = logit[qi][200 + h * 5 + 1];
        float ob2 = logit[qi][200 + h * 5 + 2];
        float ob3 = logit[qi][200 + h * 5 + 3];
        float ob4 = logit[qi][200 + h * 5 + 4];
        float cx = rw0 + ob0 * 0.125f * rw3;
        float cy = rw1 + ob1 * 0.125f * rw4;
        float bw = rw3 + ob2 * 0.125f * rw3;
        float bh = rw4 + ob3 * 0.125f * rw4;
        float ang = (rw6 + ob4 * 0.0625f) * 6.283185307179586f;
        float ca = cosf(ang), sa = sinf(ang);
        float sw = fmaxf(bw, 0.f), sh = fmaxf(bh, 0.f);
        float Wff = (float)Wf, Hff = (float)Hf;
#pragma unroll
        for (int p = 0; p < 25; p++) {
            int pi = p / 5, pj = p % 5;
            float g0 = ((float)(pj - 2) / 5.0f) * sw;  // jj component * relu(size_x)
            float g1 = ((float)(pi - 2) / 5.0f) * sh;  // ii component * relu(size_y)
            float gridx = cx + g0 * ca - g1 * sa;
            float gridy = cy + g0 * sa + g1 * ca;
            float gx = gridx * Wff - 0.5f;
            float gy = gridy * Hff - 0.5f;
            float x0f = floorf(gx), y0f = floorf(gy);
            int x0 = (int)x0f, y0 = (int)y0f;
            float wx1 = gx - x0f, wy1 = gy - y0f;
            float wx0 = 1.f - wx1, wy0 = 1.f - wy1;
            int x1 = x0 + 1, y1 = y0 + 1;
            bool vx0 = (x0 >= 0) && (x0 < Wf), vx1 = (x1 >= 0) && (x1 < Wf);
            bool vy0 = (y0 >= 0) && (y0 < Hf), vy1 = (y1 >= 0) && (y1 < Hf);
            int cx0 = min(max(x0, 0), Wf - 1), cx1 = min(max(x1, 0), Wf - 1);
            int cy0 = min(max(y0, 0), Hf - 1), cy1 = min(max(y1, 0), Hf - 1);
            float a = e[p];
            float4 wv;
            wv.x = (vy0 && vx0) ? a * wy0 * wx0 : 0.f;
            wv.y = (vy0 && vx1) ? a * wy0 * wx1 : 0.f;
            wv.z = (vy1 && vx0) ? a * wy1 * wx0 : 0.f;
            wv.w = (vy1 && vx1) ? a * wy1 * wx1 : 0.f;
            int4 lv;
            lv.x = cy0 * Wf + cx0;
            lv.y = cy0 * Wf + cx1;
            lv.z = cy1 * Wf + cx0;
            lv.w = cy1 * Wf + cx1;
            wts[base + p] = wv;
            lins[base + p] = lv;
        }
    }
}

// One 32-lane half-wave per (b,q,h); lane = head-dim. 25 points x 4 gathers.
__global__ __launch_bounds__(256) void sample_kernel(
    const float* __restrict__ v,        // B*LV*256, [b][lv][h][dh]
    const float4* __restrict__ wts,
    const int4* __restrict__ lins,
    float* __restrict__ out_heads,      // MQ*256
    const int* __restrict__ Hf_p, const int* __restrict__ Wf_p, int LQ)
{
    int Hf = *Hf_p, Wf = *Wf_p;
    int LV = Hf * Wf;
    int tid = threadIdx.x;
    int half = tid >> 5, lane = tid & 31;
    long long idx = (long long)blockIdx.x * 8 + half;   // (m*8 + h)
    int h = (int)(idx & 7);
    long long m = idx >> 3;                             // 0..MQ-1
    int b = (int)(m / LQ);
    const float* vbh = v + (size_t)b * LV * 256 + h * 32 + lane;
    size_t base = (size_t)idx * 25;
    float acc = 0.f;
    for (int p = 0; p < 25; ++p) {
        float4 w = wts[base + p];
        int4 L = lins[base + p];
        acc += w.x * vbh[(size_t)L.x << 8];
        acc += w.y * vbh[(size_t)L.y << 8];
        acc += w.z * vbh[(size_t)L.z << 8];
        acc += w.w * vbh[(size_t)L.w << 8];
    }
    out_heads[(size_t)m * 256 + h * 32 + lane] = acc;
}

extern "C" void kernel_launch(void* const* d_in, const int* in_sizes, int n_in,
                              void* d_out, int out_size, void* d_ws, size_t ws_size,
                              hipStream_t stream) {
    const float* query       = (const float*)d_in[0];
    const float* value       = (const float*)d_in[1];
    const float* ref_windows = (const float*)d_in[2];
    const float* W_box       = (const float*)d_in[3];
    const float* b_box       = (const float*)d_in[4];
    const float* W_attn      = (const float*)d_in[5];
    const float* b_attn      = (const float*)d_in[6];
    const float* W_value     = (const float*)d_in[7];
    const float* b_value     = (const float*)d_in[8];
    const float* W_out       = (const float*)d_in[9];
    const float* b_out       = (const float*)d_in[10];
    const int*   Hf          = (const int*)d_in[11];
    const int*   Wf          = (const int*)d_in[12];

    const int M1 = in_sizes[1] / 256;  // B*LV = 70688
    const int MQ = in_sizes[0] / 256;  // B*LQ = 8192
    const int LQ = MQ / 2;             // B = 2

    float*  v         = (float*)d_ws;
    float*  out_heads = v + (size_t)M1 * 256;
    float4* wts       = (float4*)(out_heads + (size_t)MQ * 256);
    int4*   lins      = (int4*)(wts + (size_t)MQ * 200);

    float* out0     = (float*)d_out;
    float* attn_out = out0 + (size_t)MQ * 256;

    // 1) value projection: v = value @ W_value^T + b_value
    dim3 g1((M1 + 63) / 64, 4);
    gemm_nt_bias<<<g1, 256, 0, stream>>>(value, W_value, b_value, v, M1);

    // 2) attn logits + softmax + box decode -> sample weights/indices
    attn_box_kernel<<<MQ / 16, 256, 0, stream>>>(query, ref_windows, W_attn, b_attn,
                                                 W_box, b_box, attn_out, wts, lins, Hf, Wf);

    // 3) bilinear gather + attn-weighted sum -> out_heads
    sample_kernel<<<MQ, 256, 0, stream>>>(v, wts, lins, out_heads, Hf, Wf, LQ);

    // 4) output projection: out = out_heads @ W_out^T + b_out
    dim3 g4((MQ + 63) / 64, 4);
    gemm_nt_bias<<<g4, 256, 0, stream>>>(out_heads, W_out, b_out, out0, MQ);
}

// Round 2
// 327.219 us; speedup vs baseline: 1.2689x; 1.2689x over previous
//
#include <hip/hip_runtime.h>
#include <hip/hip_bf16.h>

// Box3dAttention: B=2, LQ=4096, d=256, heads=8, head_dim=32, 5x5=25 points,
// feature map 188x188 (LV=35344).
//
// ws layout:
//   vbf       : M1*256 bf16, head-major [b*8+h][LV][32]   36.2 MB
//   out_heads : MQ*256 fp32                                 8.4 MB
//   wts       : MQ*200 float4 (attn*bilinear*valid)        26.2 MB
//   bases     : MQ*200 int2   (clamped row bases)          13.1 MB

typedef float floatx4 __attribute__((ext_vector_type(4)));
typedef short shortx8 __attribute__((ext_vector_type(8)));

static __device__ __forceinline__ unsigned short f2bf(float x) {
    unsigned int u = __float_as_uint(x);
    unsigned int r = (u + 0x7fffu + ((u >> 16) & 1u)) >> 16;
    return (unsigned short)r;
}

// C(bf16, head-major) = A(M x 256 fp32) @ W(256 x 256 fp32)^T + bias
// Block: 256 thr = 4 waves; tile 64(M) x 256(N); K-chunks of 64.
__global__ __launch_bounds__(256) void gemm_value_mfma(
    const float* __restrict__ A,
    const float* __restrict__ W,
    const float* __restrict__ bias,
    unsigned short* __restrict__ Vout,   // [b*8+h][LV][32] bf16
    int M, int LV)
{
    __shared__ unsigned short As[64 * 72];
    __shared__ unsigned short Bs[256 * 72];
    const int tid = threadIdx.x;
    const int m0 = blockIdx.x * 64;
    const int wv = tid >> 6, lane = tid & 63;
    const int lr = lane & 15, lq = lane >> 4;
    const int trow = tid >> 4;          // 0..15
    const int tcol4 = (tid & 15) * 4;   // 0,4,..,60

    floatx4 acc[16];
#pragma unroll
    for (int i = 0; i < 16; ++i) acc[i] = (floatx4){0.f, 0.f, 0.f, 0.f};

    for (int kc = 0; kc < 4; ++kc) {
        const int k0 = kc * 64;
        __syncthreads();
        // stage A: 64 rows x 64 cols -> bf16 LDS (stride 72)
#pragma unroll
        for (int pass = 0; pass < 4; ++pass) {
            int r = pass * 16 + trow;
            int gr = m0 + r; gr = gr < M ? gr : M - 1;
            float4 a = *(const float4*)(A + (size_t)gr * 256 + k0 + tcol4);
            unsigned int p0 = (unsigned int)f2bf(a.x) | ((unsigned int)f2bf(a.y) << 16);
            unsigned int p1 = (unsigned int)f2bf(a.z) | ((unsigned int)f2bf(a.w) << 16);
            *(uint2*)(&As[r * 72 + tcol4]) = make_uint2(p0, p1);
        }
        // stage B: all 256 W rows x 64 cols
#pragma unroll
        for (int pass = 0; pass < 16; ++pass) {
            int r = pass * 16 + trow;
            float4 b = *(const float4*)(W + (size_t)r * 256 + k0 + tcol4);
            unsigned int p0 = (unsigned int)f2bf(b.x) | ((unsigned int)f2bf(b.y) << 16);
            unsigned int p1 = (unsigned int)f2bf(b.z) | ((unsigned int)f2bf(b.w) << 16);
            *(uint2*)(&Bs[r * 72 + tcol4]) = make_uint2(p0, p1);
        }
        __syncthreads();
#pragma unroll
        for (int kk = 0; kk < 64; kk += 32) {
            shortx8 af = *(const shortx8*)&As[(wv * 16 + lr) * 72 + kk + lq * 8];
#pragma unroll
            for (int th = 0; th < 2; ++th) {
                shortx8 bf[8];
#pragma unroll
                for (int j = 0; j < 8; ++j)
                    bf[j] = *(const shortx8*)&Bs[((th * 8 + j) * 16 + lr) * 72 + kk + lq * 8];
#pragma unroll
                for (int j = 0; j < 8; ++j)
                    acc[th * 8 + j] = __builtin_amdgcn_mfma_f32_16x16x32_bf16(af, bf[j], acc[th * 8 + j], 0, 0, 0);
            }
        }
    }
    // epilogue: C/D layout col=lane&15, row=(lane>>4)*4+reg
    const int mrow_base = m0 + wv * 16 + lq * 4;
#pragma unroll
    for (int tn = 0; tn < 16; ++tn) {
        int n = tn * 16 + lr;
        float bv = bias[n];
        int h = n >> 5, dh = n & 31;
#pragma unroll
        for (int r = 0; r < 4; ++r) {
            int m = mrow_base + r;
            if (m < M) {
                int b = (m >= LV) ? 1 : 0;
                int lv = m - b * LV;
                Vout[((size_t)(b * 8 + h) * LV + lv) * 32 + dh] = f2bf(acc[tn][r] + bv);
            }
        }
    }
}

// fp32 tiled GEMM for the small out-projection: C = A @ W^T + bias
__global__ __launch_bounds__(256) void gemm_nt_bias(
    const float* __restrict__ A, const float* __restrict__ W,
    const float* __restrict__ bias, float* __restrict__ C, int M)
{
    const int K = 256, N = 256;
    __shared__ float As[16][68];
    __shared__ float Bs[16][68];
    int tid = threadIdx.x;
    int tcol = tid & 15, trow = tid >> 4;
    int m0 = blockIdx.x * 64, n0 = blockIdx.y * 64;
    int lr = tid >> 2, lc = (tid & 3) << 2;
    float acc[4][4] = {};
    for (int k0 = 0; k0 < K; k0 += 16) {
        int arow = m0 + lr; if (arow > M - 1) arow = M - 1;
        float4 av = *(const float4*)(A + (size_t)arow * K + k0 + lc);
        float4 wv = *(const float4*)(W + (size_t)(n0 + lr) * K + k0 + lc);
        __syncthreads();
        As[lc + 0][lr] = av.x; As[lc + 1][lr] = av.y; As[lc + 2][lr] = av.z; As[lc + 3][lr] = av.w;
        Bs[lc + 0][lr] = wv.x; Bs[lc + 1][lr] = wv.y; Bs[lc + 2][lr] = wv.z; Bs[lc + 3][lr] = wv.w;
        __syncthreads();
#pragma unroll
        for (int k = 0; k < 16; ++k) {
            float4 a4 = *(const float4*)&As[k][trow << 2];
            float4 b4 = *(const float4*)&Bs[k][tcol << 2];
            float a[4] = {a4.x, a4.y, a4.z, a4.w};
            float bb[4] = {b4.x, b4.y, b4.z, b4.w};
#pragma unroll
            for (int i = 0; i < 4; i++)
#pragma unroll
                for (int j = 0; j < 4; j++) acc[i][j] += a[i] * bb[j];
        }
    }
#pragma unroll
    for (int i = 0; i < 4; i++) {
        int m = m0 + trow * 4 + i;
        if (m >= M) continue;
#pragma unroll
        for (int j = 0; j < 4; j++) {
            int n = n0 + tcol * 4 + j;
            C[(size_t)m * N + n] = acc[i][j] + bias[n];
        }
    }
}

// One block = 16 queries: attn+box logits, softmax, box decode -> row bases + weights.
__global__ __launch_bounds__(256) void attn_box_kernel(
    const float* __restrict__ query,
    const float* __restrict__ ref_windows,
    const float* __restrict__ W_attn, const float* __restrict__ b_attn,
    const float* __restrict__ W_box,  const float* __restrict__ b_box,
    float* __restrict__ attn_out,
    float4* __restrict__ wts,
    int2* __restrict__ bases,
    const int* __restrict__ Hf_p, const int* __restrict__ Wf_p)
{
    __shared__ float q_lds[16][256];
    __shared__ float logit[16][240];
    __shared__ float rw_lds[16][8];
    int tid = threadIdx.x;
    int m0 = blockIdx.x * 16;
#pragma unroll
    for (int r = 0; r < 16; ++r)
        q_lds[r][tid] = query[(size_t)(m0 + r) * 256 + tid];
    if (tid < 112) rw_lds[tid / 7][tid % 7] = ref_windows[(size_t)m0 * 7 + tid];
    __syncthreads();
    if (tid < 240) {
        const float* Wrow; float bz;
        if (tid < 200) { Wrow = W_attn + (size_t)tid * 256; bz = b_attn[tid]; }
        else           { Wrow = W_box + (size_t)(tid - 200) * 256; bz = b_box[tid - 200]; }
        float acc[16];
#pragma unroll
        for (int qi = 0; qi < 16; qi++) acc[qi] = bz;
        for (int k = 0; k < 256; k += 4) {
            float4 w = *(const float4*)(Wrow + k);
#pragma unroll
            for (int qi = 0; qi < 16; qi++) {
                float4 qv = *(const float4*)&q_lds[qi][k];
                acc[qi] += w.x * qv.x + w.y * qv.y + w.z * qv.z + w.w * qv.w;
            }
        }
#pragma unroll
        for (int qi = 0; qi < 16; qi++) logit[qi][tid] = acc[qi];
    }
    __syncthreads();
    if (tid < 128) {
        int qi = tid >> 3, h = tid & 7;
        size_t m = (size_t)m0 + qi;
        float e[25];
        float mx = -1e30f;
#pragma unroll
        for (int p = 0; p < 25; p++) mx = fmaxf(mx, logit[qi][h * 25 + p]);
        float s = 0.f;
#pragma unroll
        for (int p = 0; p < 25; p++) { e[p] = expf(logit[qi][h * 25 + p] - mx); s += e[p]; }
        float inv = 1.f / s;
        size_t base = (m * 8 + h) * 25;
#pragma unroll
        for (int p = 0; p < 25; p++) { e[p] *= inv; attn_out[base + p] = e[p]; }

        int Hf = *Hf_p, Wf = *Wf_p;
        float rw0 = rw_lds[qi][0], rw1 = rw_lds[qi][1], rw3 = rw_lds[qi][3],
              rw4 = rw_lds[qi][4], rw6 = rw_lds[qi][6];
        float ob0 = logit[qi][200 + h * 5 + 0];
        float ob1 = logit[qi][200 + h * 5 + 1];
        float ob2 = logit[qi][200 + h * 5 + 2];
        float ob3 = logit[qi][200 + h * 5 + 3];
        float ob4 = logit[qi][200 + h * 5 + 4];
        float cx = rw0 + ob0 * 0.125f * rw3;
        float cy = rw1 + ob1 * 0.125f * rw4;
        float bw = rw3 + ob2 * 0.125f * rw3;
        float bh = rw4 + ob3 * 0.125f * rw4;
        float ang = (rw6 + ob4 * 0.0625f) * 6.283185307179586f;
        float ca = cosf(ang), sa = sinf(ang);
        float sw = fmaxf(bw, 0.f), sh = fmaxf(bh, 0.f);
        float Wff = (float)Wf, Hff = (float)Hf;
#pragma unroll
        for (int p = 0; p < 25; p++) {
            int pi = p / 5, pj = p % 5;
            float g0 = ((float)(pj - 2) / 5.0f) * sw;
            float g1 = ((float)(pi - 2) / 5.0f) * sh;
            float gridx = cx + g0 * ca - g1 * sa;
            float gridy = cy + g0 * sa + g1 * ca;
            float gx = gridx * Wff - 0.5f;
            float gy = gridy * Hff - 0.5f;
            float x0f = floorf(gx), y0f = floorf(gy);
            int x0 = (int)x0f, y0 = (int)y0f;
            float wx1 = gx - x0f, wy1 = gy - y0f;
            float wx0 = 1.f - wx1, wy0 = 1.f - wy1;
            int y1 = y0 + 1;
            // x pair re-based to bx = clamp(x0, 0, Wf-2); columns (bx, bx+1)
            int bx; float wl, wr;
            if (x0 >= 0 && x0 <= Wf - 2)      { bx = x0;      wl = wx0; wr = wx1; }
            else if (x0 == -1)                { bx = 0;       wl = wx1; wr = 0.f; }
            else if (x0 == Wf - 1)            { bx = Wf - 2;  wl = 0.f; wr = wx0; }
            else                              { bx = 0;       wl = 0.f; wr = 0.f; }
            float wy0v = (y0 >= 0 && y0 < Hf) ? wy0 : 0.f;
            float wy1v = (y1 >= 0 && y1 < Hf) ? wy1 : 0.f;
            int cy0 = min(max(y0, 0), Hf - 1), cy1 = min(max(y1, 0), Hf - 1);
            float a = e[p];
            float4 wv;
            wv.x = a * wy0v * wl;  // (row0, left col)
            wv.y = a * wy0v * wr;  // (row0, right col)
            wv.z = a * wy1v * wl;
            wv.w = a * wy1v * wr;
            int2 rv;
            rv.x = cy0 * Wf + bx;
            rv.y = cy1 * Wf + bx;
            wts[base + p] = wv;
            bases[base + p] = rv;
        }
    }
}

// One block per query; 8 x 32-lane groups (one per head).
// Per point: 2 x 128B coalesced loads cover both bilinear columns.
__global__ __launch_bounds__(256) void sample_kernel(
    const unsigned short* __restrict__ v,  // bf16 [b*8+h][LV][32]
    const float4* __restrict__ wts,
    const int2* __restrict__ bases,
    float* __restrict__ out_heads,         // MQ x 256 fp32
    int LV, int LQ)
{
    const int tid = threadIdx.x;
    const int h = tid >> 5, l = tid & 31;
    const int m = blockIdx.x;
    const int b = (m >= LQ) ? 1 : 0;
    const unsigned int* vw = (const unsigned int*)(v + ((size_t)(b * 8 + h) * LV) * 32);
    const size_t base = ((size_t)m * 8 + h) * 25;
    const int colsel = l >> 4;
    float a0 = 0.f, a1 = 0.f;
#pragma unroll 5
    for (int p = 0; p < 25; ++p) {
        float4 w = wts[base + p];
        int2 rb = bases[base + p];
        unsigned int u0 = vw[(size_t)rb.x * 16 + l];
        unsigned int u1 = vw[(size_t)rb.y * 16 + l];
        float w0 = colsel ? w.y : w.x;
        float w1 = colsel ? w.w : w.z;
        float lo0 = __uint_as_float(u0 << 16);
        float hi0 = __uint_as_float(u0 & 0xffff0000u);
        float lo1 = __uint_as_float(u1 << 16);
        float hi1 = __uint_as_float(u1 & 0xffff0000u);
        a0 += w0 * lo0 + w1 * lo1;
        a1 += w0 * hi0 + w1 * hi1;
    }
    a0 += __shfl_xor(a0, 16, 32);
    a1 += __shfl_xor(a1, 16, 32);
    if (l < 16) {
        float2 o = make_float2(a0, a1);
        *(float2*)(out_heads + (size_t)m * 256 + h * 32 + 2 * l) = o;
    }
}

extern "C" void kernel_launch(void* const* d_in, const int* in_sizes, int n_in,
                              void* d_out, int out_size, void* d_ws, size_t ws_size,
                              hipStream_t stream) {
    const float* query       = (const float*)d_in[0];
    const float* value       = (const float*)d_in[1];
    const float* ref_windows = (const float*)d_in[2];
    const float* W_box       = (const float*)d_in[3];
    const float* b_box       = (const float*)d_in[4];
    const float* W_attn      = (const float*)d_in[5];
    const float* b_attn      = (const float*)d_in[6];
    const float* W_value     = (const float*)d_in[7];
    const float* b_value     = (const float*)d_in[8];
    const float* W_out       = (const float*)d_in[9];
    const float* b_out       = (const float*)d_in[10];
    const int*   Hf          = (const int*)d_in[11];
    const int*   Wf          = (const int*)d_in[12];

    const int M1 = in_sizes[1] / 256;  // B*LV = 70688
    const int MQ = in_sizes[0] / 256;  // B*LQ = 8192
    const int LQ = MQ / 2;             // B = 2
    const int LV = M1 / 2;

    unsigned short* vbf      = (unsigned short*)d_ws;
    float*          out_heads= (float*)(vbf + (size_t)M1 * 256);
    float4*         wts      = (float4*)(out_heads + (size_t)MQ * 256);
    int2*           bases    = (int2*)(wts + (size_t)MQ * 200);

    float* out0     = (float*)d_out;
    float* attn_out = out0 + (size_t)MQ * 256;

    // 1) value projection (bf16 MFMA) -> head-major bf16 v
    gemm_value_mfma<<<(M1 + 63) / 64, 256, 0, stream>>>(value, W_value, b_value, vbf, M1, LV);

    // 2) attn logits + softmax + box decode -> weights / row bases
    attn_box_kernel<<<MQ / 16, 256, 0, stream>>>(query, ref_windows, W_attn, b_attn,
                                                 W_box, b_box, attn_out, wts, bases, Hf, Wf);

    // 3) bilinear gather (bf16, paired columns) -> out_heads
    sample_kernel<<<MQ, 256, 0, stream>>>(vbf, wts, bases, out_heads, LV, LQ);

    // 4) output projection
    dim3 g4((MQ + 63) / 64, 4);
    gemm_nt_bias<<<g4, 256, 0, stream>>>(out_heads, W_out, b_out, out0, MQ);
}

// Round 3
// 268.621 us; speedup vs baseline: 1.5457x; 1.2181x over previous
//
#include <hip/hip_runtime.h>

// Box3dAttention: B=2, LQ=4096, d=256, heads=8, head_dim=32, 5x5=25 points,
// feature map 188x188 (LV=35344).
//
// Pipeline:
//  K0 convert : value fp32 -> bf16 (row-major), W_value -> bf16, pad [W_attn;W_box;0] fp32 + bias
//  K1 value GEMM : m97-style bf16 MFMA (128x128 tile, BK=64, global_load_lds x16)
//                  -> Vout bf16 head-major [b*8+h][LV][32] + bias
//  K2 logits GEMM: fp32 tiled (accuracy for box offsets) -> logits [MQ][256]
//  K3 fused decode+sample: per-query block; softmax + box decode in LDS + bilinear gather
//  K4 out-proj fp32 GEMM

typedef float floatx4 __attribute__((ext_vector_type(4)));
typedef short shortx8 __attribute__((ext_vector_type(8)));

static __device__ __forceinline__ unsigned short f2bf(float x) {
    unsigned int u = __float_as_uint(x);
    return (unsigned short)((u + 0x7fffu + ((u >> 16) & 1u)) >> 16);
}
static __device__ __forceinline__ unsigned int pack2(float a, float b) {
    return (unsigned int)f2bf(a) | ((unsigned int)f2bf(b) << 16);
}
static __device__ __forceinline__ void async16(const void* g, void* lds) {
    __builtin_amdgcn_global_load_lds(
        (const __attribute__((address_space(1))) unsigned int*)g,
        (__attribute__((address_space(3))) unsigned int*)lds, 16, 0, 0);
}

// ---------------- K0: conversions / packing ----------------
__global__ __launch_bounds__(256) void convert_kernel(
    const float* __restrict__ value, unsigned short* __restrict__ vbf, long long nv4,
    const float* __restrict__ W_value, unsigned short* __restrict__ wvbf,
    const float* __restrict__ W_attn, const float* __restrict__ W_box,
    float* __restrict__ Wab,
    const float* __restrict__ b_attn, const float* __restrict__ b_box,
    float* __restrict__ bab)
{
    const int NBV = 2048;
    const int blk = blockIdx.x, tid = threadIdx.x;
    if (blk < NBV) {
        for (long long i = (long long)blk * 256 + tid; i < nv4; i += (long long)NBV * 256) {
            float4 f = ((const float4*)value)[i];
            ((uint2*)vbf)[i] = make_uint2(pack2(f.x, f.y), pack2(f.z, f.w));
        }
    } else if (blk < NBV + 16) {
        int base = (blk - NBV) * 1024 + tid;
#pragma unroll
        for (int k = 0; k < 4; ++k) {
            int j = base + k * 256;   // float4 index, 16384 total
            float4 f = ((const float4*)W_value)[j];
            ((uint2*)wvbf)[j] = make_uint2(pack2(f.x, f.y), pack2(f.z, f.w));
        }
    } else if (blk < NBV + 32) {
        int base = (blk - NBV - 16) * 1024 + tid;
#pragma unroll
        for (int k = 0; k < 4; ++k) {
            int j = base + k * 256;   // float4 index into Wab
            int row = j >> 6, col = (j & 63) * 4;
            float4 f;
            if (row < 200)      f = *(const float4*)(W_attn + (size_t)row * 256 + col);
            else if (row < 240) f = *(const float4*)(W_box + (size_t)(row - 200) * 256 + col);
            else                f = make_float4(0.f, 0.f, 0.f, 0.f);
            ((float4*)Wab)[j] = f;
        }
    } else {
        bab[tid] = tid < 200 ? b_attn[tid] : (tid < 240 ? b_box[tid - 200] : 0.f);
    }
}

// ---------------- K1: bf16 MFMA value GEMM ----------------
// C(head-major bf16) = A(M x 256 bf16) @ Bw(256 x 256 bf16, row n = W row)^T + bias
__global__ __launch_bounds__(256) void gemm_value_mfma(
    const unsigned short* __restrict__ A,
    const unsigned short* __restrict__ Bw,
    const float* __restrict__ bias,
    unsigned short* __restrict__ Vout, int M, int LV)
{
    __shared__ unsigned short As[128 * 64];
    __shared__ unsigned short Bs[128 * 64];
    const int tid = threadIdx.x;
    const int wv = tid >> 6, lane = tid & 63;
    const int lr = lane & 15, lq = lane >> 4;
    const int m0 = blockIdx.x * 128, n0 = blockIdx.y * 128;
    const int wm = wv & 1, wn = wv >> 1;
    const int srow = tid >> 3;         // 0..31
    const int scol = (tid & 7) * 8;    // element col within 64

    floatx4 acc[4][4];
#pragma unroll
    for (int i = 0; i < 4; ++i)
#pragma unroll
        for (int j = 0; j < 4; ++j) acc[i][j] = (floatx4){0.f, 0.f, 0.f, 0.f};

    for (int kc = 0; kc < 4; ++kc) {
        const int k0 = kc * 64;
        __syncthreads();
#pragma unroll
        for (int i = 0; i < 4; ++i) {
            int ra = m0 + i * 32 + srow; ra = ra < M ? ra : M - 1;
            async16(A + (size_t)ra * 256 + k0 + scol, (char*)As + i * 4096 + wv * 1024);
            int rb = n0 + i * 32 + srow;
            async16(Bw + (size_t)rb * 256 + k0 + scol, (char*)Bs + i * 4096 + wv * 1024);
        }
        __syncthreads();
#pragma unroll
        for (int kk = 0; kk < 64; kk += 32) {
            shortx8 af[4], bfr[4];
#pragma unroll
            for (int t = 0; t < 4; ++t) {
                af[t]  = *(const shortx8*)&As[(wm * 64 + t * 16 + lr) * 64 + kk + lq * 8];
                bfr[t] = *(const shortx8*)&Bs[(wn * 64 + t * 16 + lr) * 64 + kk + lq * 8];
            }
#pragma unroll
            for (int ti = 0; ti < 4; ++ti)
#pragma unroll
                for (int tj = 0; tj < 4; ++tj)
                    acc[ti][tj] = __builtin_amdgcn_mfma_f32_16x16x32_bf16(af[ti], bfr[tj], acc[ti][tj], 0, 0, 0);
        }
    }
    // epilogue: C/D map col=lane&15, row=(lane>>4)*4+reg
#pragma unroll
    for (int tj = 0; tj < 4; ++tj) {
        int n = n0 + wn * 64 + tj * 16 + lr;
        float bv = bias[n];
        int h = n >> 5, dh = n & 31;
#pragma unroll
        for (int ti = 0; ti < 4; ++ti) {
#pragma unroll
            for (int r = 0; r < 4; ++r) {
                int m = m0 + wm * 64 + ti * 16 + lq * 4 + r;
                if (m < M) {
                    int b = m >= LV ? 1 : 0;
                    int lv = m - (b ? LV : 0);
                    Vout[((size_t)(b * 8 + h) * LV + lv) * 32 + dh] = f2bf(acc[ti][tj][r] + bv);
                }
            }
        }
    }
}

// ---------------- fp32 tiled GEMM (logits + out-proj) ----------------
__global__ __launch_bounds__(256) void gemm_nt_bias(
    const float* __restrict__ A, const float* __restrict__ W,
    const float* __restrict__ bias, float* __restrict__ C, int M)
{
    const int K = 256, N = 256;
    __shared__ float As[16][68];
    __shared__ float Bs[16][68];
    int tid = threadIdx.x;
    int tcol = tid & 15, trow = tid >> 4;
    int m0 = blockIdx.x * 64, n0 = blockIdx.y * 64;
    int lr = tid >> 2, lc = (tid & 3) << 2;
    float acc[4][4] = {};
    for (int k0 = 0; k0 < K; k0 += 16) {
        int arow = m0 + lr; if (arow > M - 1) arow = M - 1;
        float4 av = *(const float4*)(A + (size_t)arow * K + k0 + lc);
        float4 wv = *(const float4*)(W + (size_t)(n0 + lr) * K + k0 + lc);
        __syncthreads();
        As[lc + 0][lr] = av.x; As[lc + 1][lr] = av.y; As[lc + 2][lr] = av.z; As[lc + 3][lr] = av.w;
        Bs[lc + 0][lr] = wv.x; Bs[lc + 1][lr] = wv.y; Bs[lc + 2][lr] = wv.z; Bs[lc + 3][lr] = wv.w;
        __syncthreads();
#pragma unroll
        for (int k = 0; k < 16; ++k) {
            float4 a4 = *(const float4*)&As[k][trow << 2];
            float4 b4 = *(const float4*)&Bs[k][tcol << 2];
            float a[4] = {a4.x, a4.y, a4.z, a4.w};
            float bb[4] = {b4.x, b4.y, b4.z, b4.w};
#pragma unroll
            for (int i = 0; i < 4; i++)
#pragma unroll
                for (int j = 0; j < 4; j++) acc[i][j] += a[i] * bb[j];
        }
    }
#pragma unroll
    for (int i = 0; i < 4; i++) {
        int m = m0 + trow * 4 + i;
        if (m >= M) continue;
#pragma unroll
        for (int j = 0; j < 4; j++) {
            int n = n0 + tcol * 4 + j;
            C[(size_t)m * N + n] = acc[i][j] + bias[n];
        }
    }
}

// ---------------- K3: fused decode + bilinear gather ----------------
// One block per query m. Phases: load logits -> per-head softmax scalars + box
// params -> per-(h,p) attn + sample weights (LDS) -> gather.
__global__ __launch_bounds__(256) void decode_sample_kernel(
    const unsigned short* __restrict__ v,   // bf16 [b*8+h][LV][32]
    const float* __restrict__ logits,       // MQ x 256 (240 real)
    const float* __restrict__ ref_windows,  // MQ x 7
    float* __restrict__ attn_out,           // MQ x 200
    float* __restrict__ out_heads,          // MQ x 256 fp32
    const int* __restrict__ Hf_p, const int* __restrict__ Wf_p, int LV, int LQ)
{
    __shared__ float lg[240];
    __shared__ float rw[8];
    __shared__ float prm[8][6];   // cx, cy, sw, sh, ca, sa
    __shared__ float mxinv[8][2];
    __shared__ float4 wls[200];
    __shared__ int2 bls[200];

    const int m = blockIdx.x, tid = threadIdx.x;
    const int Hf = *Hf_p, Wf = *Wf_p;
    if (tid < 240) lg[tid] = logits[(size_t)m * 256 + tid];
    if (tid < 7)   rw[tid] = ref_windows[(size_t)m * 7 + tid];
    __syncthreads();

    if (tid < 8) {
        int h = tid;
        float mx = -1e30f;
#pragma unroll
        for (int p = 0; p < 25; p++) mx = fmaxf(mx, lg[h * 25 + p]);
        float s = 0.f;
#pragma unroll
        for (int p = 0; p < 25; p++) s += expf(lg[h * 25 + p] - mx);
        mxinv[h][0] = mx; mxinv[h][1] = 1.f / s;
        float ob0 = lg[200 + h * 5 + 0];
        float ob1 = lg[200 + h * 5 + 1];
        float ob2 = lg[200 + h * 5 + 2];
        float ob3 = lg[200 + h * 5 + 3];
        float ob4 = lg[200 + h * 5 + 4];
        float cx = rw[0] + ob0 * 0.125f * rw[3];
        float cy = rw[1] + ob1 * 0.125f * rw[4];
        float bw = rw[3] + ob2 * 0.125f * rw[3];
        float bh = rw[4] + ob3 * 0.125f * rw[4];
        float ang = (rw[6] + ob4 * 0.0625f) * 6.283185307179586f;
        prm[h][0] = cx; prm[h][1] = cy;
        prm[h][2] = fmaxf(bw, 0.f); prm[h][3] = fmaxf(bh, 0.f);
        prm[h][4] = cosf(ang); prm[h][5] = sinf(ang);
    }
    __syncthreads();

    if (tid < 200) {
        int h = tid / 25, p = tid - h * 25;
        float a = expf(lg[tid] - mxinv[h][0]) * mxinv[h][1];
        attn_out[(size_t)m * 200 + tid] = a;
        int pi = p / 5, pj = p - pi * 5;
        float g0 = (float)(pj - 2) * 0.2f * prm[h][2];
        float g1 = (float)(pi - 2) * 0.2f * prm[h][3];
        float ca = prm[h][4], sa = prm[h][5];
        float gx = (prm[h][0] + g0 * ca - g1 * sa) * (float)Wf - 0.5f;
        float gy = (prm[h][1] + g0 * sa + g1 * ca) * (float)Hf - 0.5f;
        float x0f = floorf(gx), y0f = floorf(gy);
        int x0 = (int)x0f, y0 = (int)y0f;
        float wx1 = gx - x0f, wy1 = gy - y0f;
        float wx0 = 1.f - wx1, wy0 = 1.f - wy1;
        int y1 = y0 + 1;
        int bx; float wl, wr;
        if (x0 >= 0 && x0 <= Wf - 2)      { bx = x0;     wl = wx0; wr = wx1; }
        else if (x0 == -1)                { bx = 0;      wl = wx1; wr = 0.f; }
        else if (x0 == Wf - 1)            { bx = Wf - 2; wl = 0.f; wr = wx0; }
        else                              { bx = 0;      wl = 0.f; wr = 0.f; }
        float wy0v = (y0 >= 0 && y0 < Hf) ? wy0 : 0.f;
        float wy1v = (y1 >= 0 && y1 < Hf) ? wy1 : 0.f;
        int cy0 = min(max(y0, 0), Hf - 1), cy1 = min(max(y1, 0), Hf - 1);
        float4 wv4;
        wv4.x = a * wy0v * wl; wv4.y = a * wy0v * wr;
        wv4.z = a * wy1v * wl; wv4.w = a * wy1v * wr;
        wls[tid] = wv4;
        bls[tid] = make_int2(cy0 * Wf + bx, cy1 * Wf + bx);
    }
    __syncthreads();

    const int h = tid >> 5, l = tid & 31;
    const int b = (m >= LQ) ? 1 : 0;
    const unsigned int* vw = (const unsigned int*)(v + ((size_t)(b * 8 + h) * LV) * 32);
    const int colsel = l >> 4;
    float a0 = 0.f, a1 = 0.f;
#pragma unroll
    for (int p = 0; p < 25; ++p) {
        float4 w = wls[h * 25 + p];
        int2 rb = bls[h * 25 + p];
        unsigned int u0 = vw[(size_t)rb.x * 16 + l];
        unsigned int u1 = vw[(size_t)rb.y * 16 + l];
        float w0 = colsel ? w.y : w.x;
        float w1 = colsel ? w.w : w.z;
        a0 += w0 * __uint_as_float(u0 << 16) + w1 * __uint_as_float(u1 << 16);
        a1 += w0 * __uint_as_float(u0 & 0xffff0000u) + w1 * __uint_as_float(u1 & 0xffff0000u);
    }
    a0 += __shfl_xor(a0, 16, 32);
    a1 += __shfl_xor(a1, 16, 32);
    if (l < 16)
        *(float2*)(out_heads + (size_t)m * 256 + h * 32 + 2 * l) = make_float2(a0, a1);
}

extern "C" void kernel_launch(void* const* d_in, const int* in_sizes, int n_in,
                              void* d_out, int out_size, void* d_ws, size_t ws_size,
                              hipStream_t stream) {
    const float* query       = (const float*)d_in[0];
    const float* value       = (const float*)d_in[1];
    const float* ref_windows = (const float*)d_in[2];
    const float* W_box       = (const float*)d_in[3];
    const float* b_box       = (const float*)d_in[4];
    const float* W_attn      = (const float*)d_in[5];
    const float* b_attn      = (const float*)d_in[6];
    const float* W_value     = (const float*)d_in[7];
    const float* b_value     = (const float*)d_in[8];
    const float* W_out       = (const float*)d_in[9];
    const float* b_out       = (const float*)d_in[10];
    const int*   Hf          = (const int*)d_in[11];
    const int*   Wf          = (const int*)d_in[12];

    const int M1 = in_sizes[1] / 256;  // B*LV = 70688
    const int MQ = in_sizes[0] / 256;  // B*LQ = 8192
    const int LQ = MQ / 2;
    const int LV = M1 / 2;

    unsigned short* vbf  = (unsigned short*)d_ws;           // M1*256 bf16
    unsigned short* wvbf = vbf + (size_t)M1 * 256;          // 65536 bf16
    unsigned short* Vout = wvbf + 65536;                     // M1*256 bf16 head-major
    float* Wab       = (float*)(Vout + (size_t)M1 * 256);    // 65536 fp32
    float* bab       = Wab + 65536;                          // 256
    float* logits    = bab + 256;                            // MQ*256
    float* out_heads = logits + (size_t)MQ * 256;            // MQ*256

    float* out0     = (float*)d_out;
    float* attn_out = out0 + (size_t)MQ * 256;

    const long long nv4 = (long long)M1 * 64;   // float4 count of value

    // K0: conversions
    convert_kernel<<<2081, 256, 0, stream>>>(value, vbf, nv4, W_value, wvbf,
                                             W_attn, W_box, Wab, b_attn, b_box, bab);
    // K1: value projection (bf16 MFMA) -> head-major bf16 Vout
    dim3 g1((M1 + 127) / 128, 2);
    gemm_value_mfma<<<g1, 256, 0, stream>>>(vbf, wvbf, b_value, Vout, M1, LV);
    // K2: logits = query @ [W_attn;W_box]^T + bias  (fp32 for box accuracy)
    dim3 g2(MQ / 64, 4);
    gemm_nt_bias<<<g2, 256, 0, stream>>>(query, Wab, bab, logits, MQ);
    // K3: fused softmax + box decode + bilinear gather
    decode_sample_kernel<<<MQ, 256, 0, stream>>>(Vout, logits, ref_windows,
                                                 attn_out, out_heads, Hf, Wf, LV, LQ);
    // K4: output projection
    gemm_nt_bias<<<g2, 256, 0, stream>>>(out_heads, W_out, b_out, out0, MQ);
}

// Round 7
// 249.211 us; speedup vs baseline: 1.6661x; 1.0779x over previous
//
#include <hip/hip_runtime.h>

// Box3dAttention: B=2, LQ=4096, d=256, heads=8, head_dim=32, 5x5=25 points,
// feature map 188x188 (LV=35344).
//
// Round 7 = round 6 with decode_sample rw-load fixed: the old `else if
// (tid < 296)` needed 296 threads in a 256-thread block, leaving rw[2..7]
// uninitialized (the round-4 NaN and round-6 0.318 both trace to this).
//
// Pipeline:
//  K0 convert    : value->bf16, W_value/[W_attn;W_box]pad/W_out->bf16, bias pad
//  K1 gemm<1>    : vbf @ wvbf^T + b_value -> Vout bf16 head-major [b*8+h][LV][32]
//  K2 gemm_nt    : fp32 VALU logits = query @ [W_attn;W_box]^T + b  (accuracy for box)
//  K3 decode_sample: block=(slice s=b*8+h, 8 queries), s = fast grid dim -> XCD s%8;
//                  softmax + box decode + bilinear gather (paired-column bf16 rows)
//  K3.5 convert_oh: out_heads fp32 -> bf16
//  K4 gemm<0>    : ohbf @ wobf^T + b_out -> out fp32

typedef float floatx4 __attribute__((ext_vector_type(4)));
typedef short shortx8 __attribute__((ext_vector_type(8)));

static __device__ __forceinline__ unsigned short f2bf(float x) {
    unsigned int u = __float_as_uint(x);
    return (unsigned short)((u + 0x7fffu + ((u >> 16) & 1u)) >> 16);
}
static __device__ __forceinline__ unsigned int pack2(float a, float b) {
    return (unsigned int)f2bf(a) | ((unsigned int)f2bf(b) << 16);
}
static __device__ __forceinline__ void async16(const void* g, void* lds) {
    __builtin_amdgcn_global_load_lds(
        (const __attribute__((address_space(1))) unsigned int*)g,
        (__attribute__((address_space(3))) unsigned int*)lds, 16, 0, 0);
}

// ---------------- K0: conversions ----------------
// grid = 2048 (value) + 16 (W_value) + 16 (Wab) + 16 (W_out) + 1 (bias) = 2097
__global__ __launch_bounds__(256) void convert_kernel(
    const float* __restrict__ value, unsigned short* __restrict__ vbf, long long nv4,
    const float* __restrict__ W_value, unsigned short* __restrict__ wvbf,
    const float* __restrict__ W_attn, const float* __restrict__ W_box,
    unsigned short* __restrict__ wabf, float* __restrict__ Wab,
    const float* __restrict__ W_out, unsigned short* __restrict__ wobf,
    const float* __restrict__ b_attn, const float* __restrict__ b_box,
    float* __restrict__ bab)
{
    const int NBV = 2048;
    const int blk = blockIdx.x, tid = threadIdx.x;
    if (blk < NBV) {
        for (long long i = (long long)blk * 256 + tid; i < nv4; i += (long long)NBV * 256) {
            float4 f = ((const float4*)value)[i];
            ((uint2*)vbf)[i] = make_uint2(pack2(f.x, f.y), pack2(f.z, f.w));
        }
    } else if (blk < NBV + 16) {
        int base = (blk - NBV) * 1024 + tid;
#pragma unroll
        for (int k = 0; k < 4; ++k) {
            int j = base + k * 256;
            float4 f = ((const float4*)W_value)[j];
            ((uint2*)wvbf)[j] = make_uint2(pack2(f.x, f.y), pack2(f.z, f.w));
        }
    } else if (blk < NBV + 32) {
        int base = (blk - NBV - 16) * 1024 + tid;
#pragma unroll
        for (int k = 0; k < 4; ++k) {
            int j = base + k * 256;
            int row = j >> 6, col = (j & 63) * 4;
            float4 f;
            if (row < 200)      f = *(const float4*)(W_attn + (size_t)row * 256 + col);
            else if (row < 240) f = *(const float4*)(W_box + (size_t)(row - 200) * 256 + col);
            else                f = make_float4(0.f, 0.f, 0.f, 0.f);
            ((uint2*)wabf)[j] = make_uint2(pack2(f.x, f.y), pack2(f.z, f.w));
            ((float4*)Wab)[j] = f;
        }
    } else if (blk < NBV + 48) {
        int base = (blk - NBV - 32) * 1024 + tid;
#pragma unroll
        for (int k = 0; k < 4; ++k) {
            int j = base + k * 256;
            float4 f = ((const float4*)W_out)[j];
            ((uint2*)wobf)[j] = make_uint2(pack2(f.x, f.y), pack2(f.z, f.w));
        }
    } else {
        bab[tid] = tid < 200 ? b_attn[tid] : (tid < 240 ? b_box[tid - 200] : 0.f);
    }
}

// ---------------- K3.5: out_heads fp32 -> bf16 ----------------
__global__ __launch_bounds__(256) void convert_oh(
    const float* __restrict__ src, unsigned short* __restrict__ dst)
{
    int base = blockIdx.x * 256 + threadIdx.x;   // 256 blocks
#pragma unroll
    for (int k = 0; k < 8; ++k) {
        int j = base + k * 65536;
        float4 f = ((const float4*)src)[j];
        ((uint2*)dst)[j] = make_uint2(pack2(f.x, f.y), pack2(f.z, f.w));
    }
}

// ---------------- bf16 MFMA GEMM (round-3-verified structure) ----------------
// C = A(M x 256 bf16) @ Bw(256 x 256 bf16)^T + bias
// OUTMODE 0: C fp32 row-major [M][256]; OUTMODE 1: C bf16 head-major [b*8+h][LV][32]
// 256 threads = 4 waves; tile 128(M) x 128(N); grid (ceil(M/128), 2).
template <int OUTMODE>
__global__ __launch_bounds__(256) void gemm_bf16(
    const unsigned short* __restrict__ A,
    const unsigned short* __restrict__ Bw,
    const float* __restrict__ bias,
    void* __restrict__ Cv, int M, int LV)
{
    __shared__ unsigned short As[128 * 64];
    __shared__ unsigned short Bs[128 * 64];
    const int tid = threadIdx.x;
    const int wv = tid >> 6, lane = tid & 63;
    const int lr = lane & 15, lq = lane >> 4;
    const int m0 = blockIdx.x * 128, n0 = blockIdx.y * 128;
    const int wm = wv & 1, wn = wv >> 1;
    const int srow = tid >> 3;         // 0..31
    const int scol = (tid & 7) * 8;    // shorts

    floatx4 acc[4][4];
#pragma unroll
    for (int i = 0; i < 4; ++i)
#pragma unroll
        for (int j = 0; j < 4; ++j) acc[i][j] = (floatx4){0.f, 0.f, 0.f, 0.f};

    for (int kc = 0; kc < 4; ++kc) {
        const int k0 = kc * 64;
        __syncthreads();
#pragma unroll
        for (int i = 0; i < 4; ++i) {
            int ra = m0 + i * 32 + srow; ra = ra < M ? ra : M - 1;
            async16(A + (size_t)ra * 256 + k0 + scol, (char*)As + i * 4096 + wv * 1024);
            int rb = n0 + i * 32 + srow;
            async16(Bw + (size_t)rb * 256 + k0 + scol, (char*)Bs + i * 4096 + wv * 1024);
        }
        __syncthreads();
#pragma unroll
        for (int kk = 0; kk < 64; kk += 32) {
            shortx8 af[4], bfr[4];
#pragma unroll
            for (int t = 0; t < 4; ++t) {
                af[t]  = *(const shortx8*)&As[(wm * 64 + t * 16 + lr) * 64 + kk + lq * 8];
                bfr[t] = *(const shortx8*)&Bs[(wn * 64 + t * 16 + lr) * 64 + kk + lq * 8];
            }
#pragma unroll
            for (int ti = 0; ti < 4; ++ti)
#pragma unroll
                for (int tj = 0; tj < 4; ++tj)
                    acc[ti][tj] = __builtin_amdgcn_mfma_f32_16x16x32_bf16(af[ti], bfr[tj], acc[ti][tj], 0, 0, 0);
        }
    }
    // epilogue: C/D map col=lane&15, row=(lane>>4)*4+reg
#pragma unroll
    for (int tj = 0; tj < 4; ++tj) {
        int n = n0 + wn * 64 + tj * 16 + lr;
        float bv = bias[n];
#pragma unroll
        for (int ti = 0; ti < 4; ++ti) {
#pragma unroll
            for (int r = 0; r < 4; ++r) {
                int m = m0 + wm * 64 + ti * 16 + lq * 4 + r;
                if (m >= M) continue;
                float val = acc[ti][tj][r] + bv;
                if (OUTMODE == 0) {
                    ((float*)Cv)[(size_t)m * 256 + n] = val;
                } else {
                    int h = n >> 5, dh = n & 31;
                    int b = m >= LV ? 1 : 0;
                    int lv = m - (b ? LV : 0);
                    ((unsigned short*)Cv)[((size_t)(b * 8 + h) * LV + lv) * 32 + dh] = f2bf(val);
                }
            }
        }
    }
}

// ---------------- K2: fp32 tiled GEMM (logits, accuracy-critical) ----------------
__global__ __launch_bounds__(256) void gemm_nt_bias(
    const float* __restrict__ A, const float* __restrict__ W,
    const float* __restrict__ bias, float* __restrict__ C, int M)
{
    const int K = 256, N = 256;
    __shared__ float As[16][68];
    __shared__ float Bs[16][68];
    int tid = threadIdx.x;
    int tcol = tid & 15, trow = tid >> 4;
    int m0 = blockIdx.x * 64, n0 = blockIdx.y * 64;
    int lr = tid >> 2, lc = (tid & 3) << 2;
    float acc[4][4] = {};
    for (int k0 = 0; k0 < K; k0 += 16) {
        int arow = m0 + lr; if (arow > M - 1) arow = M - 1;
        float4 av = *(const float4*)(A + (size_t)arow * K + k0 + lc);
        float4 wv = *(const float4*)(W + (size_t)(n0 + lr) * K + k0 + lc);
        __syncthreads();
        As[lc + 0][lr] = av.x; As[lc + 1][lr] = av.y; As[lc + 2][lr] = av.z; As[lc + 3][lr] = av.w;
        Bs[lc + 0][lr] = wv.x; Bs[lc + 1][lr] = wv.y; Bs[lc + 2][lr] = wv.z; Bs[lc + 3][lr] = wv.w;
        __syncthreads();
#pragma unroll
        for (int k = 0; k < 16; ++k) {
            float4 a4 = *(const float4*)&As[k][trow << 2];
            float4 b4 = *(const float4*)&Bs[k][tcol << 2];
            float a[4] = {a4.x, a4.y, a4.z, a4.w};
            float bb[4] = {b4.x, b4.y, b4.z, b4.w};
#pragma unroll
            for (int i = 0; i < 4; i++)
#pragma unroll
                for (int j = 0; j < 4; j++) acc[i][j] += a[i] * bb[j];
        }
    }
#pragma unroll
    for (int i = 0; i < 4; i++) {
        int m = m0 + trow * 4 + i;
        if (m >= M) continue;
#pragma unroll
        for (int j = 0; j < 4; j++) {
            int n = n0 + tcol * 4 + j;
            C[(size_t)m * N + n] = acc[i][j] + bias[n];
        }
    }
}

// ---------------- K3: XCD-affine fused decode + bilinear gather ----------------
// grid (16, LQ/8): blockIdx.x = slice s = b*8+h (fast dim -> XCD s%8),
// blockIdx.y = query chunk of 8. 256 threads.
__global__ __launch_bounds__(256) void decode_sample_kernel(
    const unsigned short* __restrict__ v,   // bf16 [b*8+h][LV][32]
    const float* __restrict__ logits,       // MQ x 256 (240 real)
    const float* __restrict__ ref_windows,  // MQ x 7
    float* __restrict__ attn_out,           // MQ x 200
    float* __restrict__ out_heads,          // MQ x 256 fp32
    const int* __restrict__ Hf_p, const int* __restrict__ Wf_p, int LV, int LQ)
{
    __shared__ float lg[8][32];
    __shared__ float rw[8][7];
    __shared__ float prm[8][6];
    __shared__ float mxinv[8][2];
    __shared__ float4 wls[8][25];
    __shared__ int2 bls[8][25];

    const int s = blockIdx.x, c = blockIdx.y;
    const int b = s >> 3, h = s & 7;
    const int tid = threadIdx.x;
    const int Hf = *Hf_p, Wf = *Wf_p;
    const size_t mbase = (size_t)b * LQ + c * 8;

    if (tid < 240) {
        int qq = tid / 30, j = tid - qq * 30;
        int col = (j < 25) ? h * 25 + j : 200 + h * 5 + (j - 25);
        lg[qq][j] = logits[(mbase + qq) * 256 + col];
    }
    // NOTE: separate if (NOT else-if): block has only 256 threads, so the
    // rw load must reuse low-tid threads. (Round 4/6 bug: `else if (tid<296)`
    // left rw[2..7] uninitialized -> garbage boxes.)
    if (tid < 56) {
        int qq = tid / 7, k = tid - qq * 7;
        rw[qq][k] = ref_windows[(mbase + qq) * 7 + k];
    }
    __syncthreads();

    if (tid < 8) {
        int qq = tid;
        float mx = -1e30f;
#pragma unroll
        for (int p = 0; p < 25; p++) mx = fmaxf(mx, lg[qq][p]);
        float ssum = 0.f;
#pragma unroll
        for (int p = 0; p < 25; p++) ssum += expf(lg[qq][p] - mx);
        mxinv[qq][0] = mx; mxinv[qq][1] = 1.f / ssum;
        float cx = rw[qq][0] + lg[qq][25] * 0.125f * rw[qq][3];
        float cy = rw[qq][1] + lg[qq][26] * 0.125f * rw[qq][4];
        float bw = rw[qq][3] + lg[qq][27] * 0.125f * rw[qq][3];
        float bh = rw[qq][4] + lg[qq][28] * 0.125f * rw[qq][4];
        float ang = (rw[qq][6] + lg[qq][29] * 0.0625f) * 6.283185307179586f;
        prm[qq][0] = cx; prm[qq][1] = cy;
        prm[qq][2] = fmaxf(bw, 0.f); prm[qq][3] = fmaxf(bh, 0.f);
        prm[qq][4] = cosf(ang); prm[qq][5] = sinf(ang);
    }
    __syncthreads();

    if (tid < 200) {
        int qq = tid / 25, p = tid - qq * 25;
        float a = expf(lg[qq][p] - mxinv[qq][0]) * mxinv[qq][1];
        attn_out[(mbase + qq) * 200 + h * 25 + p] = a;
        int pi = p / 5, pj = p - pi * 5;
        float g0 = (float)(pj - 2) * 0.2f * prm[qq][2];
        float g1 = (float)(pi - 2) * 0.2f * prm[qq][3];
        float ca = prm[qq][4], sa = prm[qq][5];
        float gx = (prm[qq][0] + g0 * ca - g1 * sa) * (float)Wf - 0.5f;
        float gy = (prm[qq][1] + g0 * sa + g1 * ca) * (float)Hf - 0.5f;
        float x0f = floorf(gx), y0f = floorf(gy);
        int x0 = (int)x0f, y0 = (int)y0f;
        float wx1 = gx - x0f, wy1 = gy - y0f;
        float wx0 = 1.f - wx1, wy0 = 1.f - wy1;
        int y1 = y0 + 1;
        int bx; float wl, wr;
        if (x0 >= 0 && x0 <= Wf - 2)      { bx = x0;     wl = wx0; wr = wx1; }
        else if (x0 == -1)                { bx = 0;      wl = wx1; wr = 0.f; }
        else if (x0 == Wf - 1)            { bx = Wf - 2; wl = 0.f; wr = wx0; }
        else                              { bx = 0;      wl = 0.f; wr = 0.f; }
        float wy0v = (y0 >= 0 && y0 < Hf) ? wy0 : 0.f;
        float wy1v = (y1 >= 0 && y1 < Hf) ? wy1 : 0.f;
        int cy0 = min(max(y0, 0), Hf - 1), cy1 = min(max(y1, 0), Hf - 1);
        float4 wv4;
        wv4.x = a * wy0v * wl; wv4.y = a * wy0v * wr;
        wv4.z = a * wy1v * wl; wv4.w = a * wy1v * wr;
        wls[qq][p] = wv4;
        bls[qq][p] = make_int2(cy0 * Wf + bx, cy1 * Wf + bx);
    }
    __syncthreads();

    const int qq = tid >> 5, l = tid & 31;
    const unsigned int* vw = (const unsigned int*)(v + (size_t)s * LV * 32);
    const int colsel = l >> 4;
    float a0 = 0.f, a1 = 0.f;
#pragma unroll
    for (int p = 0; p < 25; ++p) {
        float4 w = wls[qq][p];
        int2 rb = bls[qq][p];
        unsigned int u0 = vw[(size_t)rb.x * 16 + l];
        unsigned int u1 = vw[(size_t)rb.y * 16 + l];
        float w0 = colsel ? w.y : w.x;
        float w1 = colsel ? w.w : w.z;
        a0 += w0 * __uint_as_float(u0 << 16) + w1 * __uint_as_float(u1 << 16);
        a1 += w0 * __uint_as_float(u0 & 0xffff0000u) + w1 * __uint_as_float(u1 & 0xffff0000u);
    }
    a0 += __shfl_xor(a0, 16, 32);
    a1 += __shfl_xor(a1, 16, 32);
    if (l < 16)
        *(float2*)(out_heads + (mbase + qq) * 256 + h * 32 + 2 * l) = make_float2(a0, a1);
}

extern "C" void kernel_launch(void* const* d_in, const int* in_sizes, int n_in,
                              void* d_out, int out_size, void* d_ws, size_t ws_size,
                              hipStream_t stream) {
    const float* query       = (const float*)d_in[0];
    const float* value       = (const float*)d_in[1];
    const float* ref_windows = (const float*)d_in[2];
    const float* W_box       = (const float*)d_in[3];
    const float* b_box       = (const float*)d_in[4];
    const float* W_attn      = (const float*)d_in[5];
    const float* b_attn      = (const float*)d_in[6];
    const float* W_value     = (const float*)d_in[7];
    const float* b_value     = (const float*)d_in[8];
    const float* W_out       = (const float*)d_in[9];
    const float* b_out       = (const float*)d_in[10];
    const int*   Hf          = (const int*)d_in[11];
    const int*   Wf          = (const int*)d_in[12];

    const int M1 = in_sizes[1] / 256;  // B*LV = 70688
    const int MQ = in_sizes[0] / 256;  // B*LQ = 8192
    const int LQ = MQ / 2;
    const int LV = M1 / 2;

    unsigned short* vbf  = (unsigned short*)d_ws;                 // M1*256
    unsigned short* Vout = vbf + (size_t)M1 * 256;                // M1*256
    unsigned short* ohbf = Vout + (size_t)M1 * 256;               // MQ*256
    unsigned short* wvbf = ohbf + (size_t)MQ * 256;               // 65536
    unsigned short* wabf = wvbf + 65536;                          // 65536
    unsigned short* wobf = wabf + 65536;                          // 65536
    float* Wab       = (float*)(wobf + 65536);                    // 65536 fp32
    float* bab       = Wab + 65536;                               // 256
    float* logits    = bab + 256;                                 // MQ*256
    float* out_heads = logits + (size_t)MQ * 256;                 // MQ*256

    float* out0     = (float*)d_out;
    float* attn_out = out0 + (size_t)MQ * 256;

    const long long nv4 = (long long)M1 * 64;

    // K0: conversions (2048 value blocks + 16+16+16 weight blocks + 1 bias = 2097)
    convert_kernel<<<2097, 256, 0, stream>>>(value, vbf, nv4, W_value, wvbf,
                                             W_attn, W_box, wabf, Wab,
                                             W_out, wobf, b_attn, b_box, bab);
    // K1: value projection -> head-major bf16 Vout
    dim3 g1((M1 + 127) / 128, 2);
    gemm_bf16<1><<<g1, 256, 0, stream>>>(vbf, wvbf, b_value, Vout, M1, LV);
    // K2: logits fp32 (accuracy-critical box path)
    dim3 g2(MQ / 64, 4);
    gemm_nt_bias<<<g2, 256, 0, stream>>>(query, Wab, bab, logits, MQ);
    // K3: XCD-affine fused softmax + box decode + gather
    decode_sample_kernel<<<dim3(16, LQ / 8), 256, 0, stream>>>(
        Vout, logits, ref_windows, attn_out, out_heads, Hf, Wf, LV, LQ);
    // K3.5: out_heads -> bf16
    convert_oh<<<256, 256, 0, stream>>>(out_heads, ohbf);
    // K4: output projection via bf16 MFMA
    dim3 g4(MQ / 128, 2);
    gemm_bf16<0><<<g4, 256, 0, stream>>>(ohbf, wobf, b_out, out0, MQ, LV);
}

// Round 8
// 222.240 us; speedup vs baseline: 1.8683x; 1.1214x over previous
//
#include <hip/hip_runtime.h>

// Box3dAttention: B=2, LQ=4096, d=256, heads=8, head_dim=32, 5x5=25 points,
// feature map 188x188 (LV=35344).
//
// Round 8 = round 7 +
//  (a) decode_sample gather loop: one ds_read_b128 packed record per point
//      {w_row0,w_row1,off0,off1} per column-half; no weight cndmask; bf16 out.
//  (b) gemm_bf16: MFMA operand swap -> lane holds 4 consecutive n -> vectorized
//      epilogue stores (8B/16B instead of 64x2B scatter in head-major mode).
//  (c) convert_oh deleted (decode writes bf16 out_heads directly).
//
// Pipeline:
//  K0 convert    : value->bf16, W_value/[W_attn;W_box]pad/W_out->bf16, bias pad
//  K1 gemm<1>    : vbf @ wvbf^T + b_value -> Vout bf16 head-major [b*8+h][LV][32]
//  K2 gemm_nt    : fp32 VALU logits = query @ [W_attn;W_box]^T + b (box accuracy)
//  K3 decode_sample: block=(slice s=b*8+h, 8 q); s fast grid dim -> XCD s%8
//  K4 gemm<0>    : ohbf @ wobf^T + b_out -> out fp32

typedef float floatx4 __attribute__((ext_vector_type(4)));
typedef short shortx8 __attribute__((ext_vector_type(8)));

static __device__ __forceinline__ unsigned short f2bf(float x) {
    unsigned int u = __float_as_uint(x);
    return (unsigned short)((u + 0x7fffu + ((u >> 16) & 1u)) >> 16);
}
static __device__ __forceinline__ unsigned int pack2(float a, float b) {
    return (unsigned int)f2bf(a) | ((unsigned int)f2bf(b) << 16);
}
static __device__ __forceinline__ void async16(const void* g, void* lds) {
    __builtin_amdgcn_global_load_lds(
        (const __attribute__((address_space(1))) unsigned int*)g,
        (__attribute__((address_space(3))) unsigned int*)lds, 16, 0, 0);
}

// ---------------- K0: conversions ----------------
// grid = 2048 (value) + 16 (W_value) + 16 (Wab) + 16 (W_out) + 1 (bias) = 2097
__global__ __launch_bounds__(256) void convert_kernel(
    const float* __restrict__ value, unsigned short* __restrict__ vbf, long long nv4,
    const float* __restrict__ W_value, unsigned short* __restrict__ wvbf,
    const float* __restrict__ W_attn, const float* __restrict__ W_box,
    unsigned short* __restrict__ wabf, float* __restrict__ Wab,
    const float* __restrict__ W_out, unsigned short* __restrict__ wobf,
    const float* __restrict__ b_attn, const float* __restrict__ b_box,
    float* __restrict__ bab)
{
    const int NBV = 2048;
    const int blk = blockIdx.x, tid = threadIdx.x;
    if (blk < NBV) {
        for (long long i = (long long)blk * 256 + tid; i < nv4; i += (long long)NBV * 256) {
            float4 f = ((const float4*)value)[i];
            ((uint2*)vbf)[i] = make_uint2(pack2(f.x, f.y), pack2(f.z, f.w));
        }
    } else if (blk < NBV + 16) {
        int base = (blk - NBV) * 1024 + tid;
#pragma unroll
        for (int k = 0; k < 4; ++k) {
            int j = base + k * 256;
            float4 f = ((const float4*)W_value)[j];
            ((uint2*)wvbf)[j] = make_uint2(pack2(f.x, f.y), pack2(f.z, f.w));
        }
    } else if (blk < NBV + 32) {
        int base = (blk - NBV - 16) * 1024 + tid;
#pragma unroll
        for (int k = 0; k < 4; ++k) {
            int j = base + k * 256;
            int row = j >> 6, col = (j & 63) * 4;
            float4 f;
            if (row < 200)      f = *(const float4*)(W_attn + (size_t)row * 256 + col);
            else if (row < 240) f = *(const float4*)(W_box + (size_t)(row - 200) * 256 + col);
            else                f = make_float4(0.f, 0.f, 0.f, 0.f);
            ((uint2*)wabf)[j] = make_uint2(pack2(f.x, f.y), pack2(f.z, f.w));
            ((float4*)Wab)[j] = f;
        }
    } else if (blk < NBV + 48) {
        int base = (blk - NBV - 32) * 1024 + tid;
#pragma unroll
        for (int k = 0; k < 4; ++k) {
            int j = base + k * 256;
            float4 f = ((const float4*)W_out)[j];
            ((uint2*)wobf)[j] = make_uint2(pack2(f.x, f.y), pack2(f.z, f.w));
        }
    } else {
        bab[tid] = tid < 200 ? b_attn[tid] : (tid < 240 ? b_box[tid - 200] : 0.f);
    }
}

// ---------------- bf16 MFMA GEMM (swapped-operand epilogue) ----------------
// C = A(M x 256 bf16) @ Bw(256 x 256 bf16)^T + bias
// mfma(bfr, af, acc) => D^T layout: col(lane&15)=m, row(lq*4+r)=n; lane holds
// 4 CONSECUTIVE n per (ti,tj) -> vectorized stores.
// OUTMODE 0: C fp32 row-major [M][256]; OUTMODE 1: C bf16 head-major [b*8+h][LV][32]
template <int OUTMODE>
__global__ __launch_bounds__(256) void gemm_bf16(
    const unsigned short* __restrict__ A,
    const unsigned short* __restrict__ Bw,
    const float* __restrict__ bias,
    void* __restrict__ Cv, int M, int LV)
{
    __shared__ unsigned short As[128 * 64];
    __shared__ unsigned short Bs[128 * 64];
    const int tid = threadIdx.x;
    const int wv = tid >> 6, lane = tid & 63;
    const int lr = lane & 15, lq = lane >> 4;
    const int m0 = blockIdx.x * 128, n0 = blockIdx.y * 128;
    const int wm = wv & 1, wn = wv >> 1;
    const int srow = tid >> 3;         // 0..31
    const int scol = (tid & 7) * 8;    // shorts

    floatx4 acc[4][4];
#pragma unroll
    for (int i = 0; i < 4; ++i)
#pragma unroll
        for (int j = 0; j < 4; ++j) acc[i][j] = (floatx4){0.f, 0.f, 0.f, 0.f};

    for (int kc = 0; kc < 4; ++kc) {
        const int k0 = kc * 64;
        __syncthreads();
#pragma unroll
        for (int i = 0; i < 4; ++i) {
            int ra = m0 + i * 32 + srow; ra = ra < M ? ra : M - 1;
            async16(A + (size_t)ra * 256 + k0 + scol, (char*)As + i * 4096 + wv * 1024);
            int rb = n0 + i * 32 + srow;
            async16(Bw + (size_t)rb * 256 + k0 + scol, (char*)Bs + i * 4096 + wv * 1024);
        }
        __syncthreads();
#pragma unroll
        for (int kk = 0; kk < 64; kk += 32) {
            shortx8 af[4], bfr[4];
#pragma unroll
            for (int t = 0; t < 4; ++t) {
                af[t]  = *(const shortx8*)&As[(wm * 64 + t * 16 + lr) * 64 + kk + lq * 8];
                bfr[t] = *(const shortx8*)&Bs[(wn * 64 + t * 16 + lr) * 64 + kk + lq * 8];
            }
#pragma unroll
            for (int ti = 0; ti < 4; ++ti)
#pragma unroll
                for (int tj = 0; tj < 4; ++tj)
                    acc[ti][tj] = __builtin_amdgcn_mfma_f32_16x16x32_bf16(bfr[tj], af[ti], acc[ti][tj], 0, 0, 0);
        }
    }
    // epilogue (transposed D): m = col = lr-indexed, n = row = lq*4 + reg
#pragma unroll
    for (int ti = 0; ti < 4; ++ti) {
        int m = m0 + wm * 64 + ti * 16 + lr;
        if (m >= M) continue;
        if (OUTMODE == 0) {
            float* Crow = (float*)Cv + (size_t)m * 256;
#pragma unroll
            for (int tj = 0; tj < 4; ++tj) {
                int nb = n0 + wn * 64 + tj * 16 + lq * 4;
                float4 bv = *(const float4*)(bias + nb);
                float4 o = make_float4(acc[ti][tj][0] + bv.x, acc[ti][tj][1] + bv.y,
                                       acc[ti][tj][2] + bv.z, acc[ti][tj][3] + bv.w);
                *(float4*)(Crow + nb) = o;
            }
        } else {
            int b = m >= LV ? 1 : 0;
            int lv = m - (b ? LV : 0);
#pragma unroll
            for (int tj = 0; tj < 4; ++tj) {
                int nb = n0 + wn * 64 + tj * 16 + lq * 4;
                float4 bv = *(const float4*)(bias + nb);
                int h = nb >> 5, dh = nb & 31;
                unsigned short* dst = (unsigned short*)Cv + ((size_t)(b * 8 + h) * LV + lv) * 32 + dh;
                *(uint2*)dst = make_uint2(pack2(acc[ti][tj][0] + bv.x, acc[ti][tj][1] + bv.y),
                                          pack2(acc[ti][tj][2] + bv.z, acc[ti][tj][3] + bv.w));
            }
        }
    }
}

// ---------------- K2: fp32 tiled GEMM (logits, accuracy-critical) ----------------
__global__ __launch_bounds__(256) void gemm_nt_bias(
    const float* __restrict__ A, const float* __restrict__ W,
    const float* __restrict__ bias, float* __restrict__ C, int M)
{
    const int K = 256, N = 256;
    __shared__ float As[16][68];
    __shared__ float Bs[16][68];
    int tid = threadIdx.x;
    int tcol = tid & 15, trow = tid >> 4;
    int m0 = blockIdx.x * 64, n0 = blockIdx.y * 64;
    int lr = tid >> 2, lc = (tid & 3) << 2;
    float acc[4][4] = {};
    for (int k0 = 0; k0 < K; k0 += 16) {
        int arow = m0 + lr; if (arow > M - 1) arow = M - 1;
        float4 av = *(const float4*)(A + (size_t)arow * K + k0 + lc);
        float4 wv = *(const float4*)(W + (size_t)(n0 + lr) * K + k0 + lc);
        __syncthreads();
        As[lc + 0][lr] = av.x; As[lc + 1][lr] = av.y; As[lc + 2][lr] = av.z; As[lc + 3][lr] = av.w;
        Bs[lc + 0][lr] = wv.x; Bs[lc + 1][lr] = wv.y; Bs[lc + 2][lr] = wv.z; Bs[lc + 3][lr] = wv.w;
        __syncthreads();
#pragma unroll
        for (int k = 0; k < 16; ++k) {
            float4 a4 = *(const float4*)&As[k][trow << 2];
            float4 b4 = *(const float4*)&Bs[k][tcol << 2];
            float a[4] = {a4.x, a4.y, a4.z, a4.w};
            float bb[4] = {b4.x, b4.y, b4.z, b4.w};
#pragma unroll
            for (int i = 0; i < 4; i++)
#pragma unroll
                for (int j = 0; j < 4; j++) acc[i][j] += a[i] * bb[j];
        }
    }
#pragma unroll
    for (int i = 0; i < 4; i++) {
        int m = m0 + trow * 4 + i;
        if (m >= M) continue;
#pragma unroll
        for (int j = 0; j < 4; j++) {
            int n = n0 + tcol * 4 + j;
            C[(size_t)m * N + n] = acc[i][j] + bias[n];
        }
    }
}

// ---------------- K3: XCD-affine fused decode + bilinear gather ----------------
// grid (16, LQ/8): blockIdx.x = slice s = b*8+h (fast dim -> XCD s%8).
__global__ __launch_bounds__(256) void decode_sample_kernel(
    const unsigned short* __restrict__ v,   // bf16 [b*8+h][LV][32]
    const float* __restrict__ logits,       // MQ x 256 (240 real)
    const float* __restrict__ ref_windows,  // MQ x 7
    float* __restrict__ attn_out,           // MQ x 200
    unsigned short* __restrict__ ohbf,      // MQ x 256 bf16
    const int* __restrict__ Hf_p, const int* __restrict__ Wf_p, int LV, int LQ)
{
    __shared__ float lg[8][32];
    __shared__ float rw[8][7];
    __shared__ float prm[8][6];
    __shared__ float mxinv[8][2];
    __shared__ uint4 pk[8][25][2];   // [q][point][colhalf] = {w_row0, w_row1, off0, off1}

    const int s = blockIdx.x, c = blockIdx.y;
    const int b = s >> 3, h = s & 7;
    const int tid = threadIdx.x;
    const int Hf = *Hf_p, Wf = *Wf_p;
    const size_t mbase = (size_t)b * LQ + c * 8;

    if (tid < 240) {
        int qq = tid / 30, j = tid - qq * 30;
        int col = (j < 25) ? h * 25 + j : 200 + h * 5 + (j - 25);
        lg[qq][j] = logits[(mbase + qq) * 256 + col];
    }
    // separate if (NOT else-if): only 256 threads in the block
    if (tid < 56) {
        int qq = tid / 7, k = tid - qq * 7;
        rw[qq][k] = ref_windows[(mbase + qq) * 7 + k];
    }
    __syncthreads();

    if (tid < 8) {
        int qq = tid;
        float mx = -1e30f;
#pragma unroll
        for (int p = 0; p < 25; p++) mx = fmaxf(mx, lg[qq][p]);
        float ssum = 0.f;
#pragma unroll
        for (int p = 0; p < 25; p++) ssum += expf(lg[qq][p] - mx);
        mxinv[qq][0] = mx; mxinv[qq][1] = 1.f / ssum;
        float cx = rw[qq][0] + lg[qq][25] * 0.125f * rw[qq][3];
        float cy = rw[qq][1] + lg[qq][26] * 0.125f * rw[qq][4];
        float bw = rw[qq][3] + lg[qq][27] * 0.125f * rw[qq][3];
        float bh = rw[qq][4] + lg[qq][28] * 0.125f * rw[qq][4];
        float ang = (rw[qq][6] + lg[qq][29] * 0.0625f) * 6.283185307179586f;
        prm[qq][0] = cx; prm[qq][1] = cy;
        prm[qq][2] = fmaxf(bw, 0.f); prm[qq][3] = fmaxf(bh, 0.f);
        prm[qq][4] = cosf(ang); prm[qq][5] = sinf(ang);
    }
    __syncthreads();

    if (tid < 200) {
        int qq = tid / 25, p = tid - qq * 25;
        float a = expf(lg[qq][p] - mxinv[qq][0]) * mxinv[qq][1];
        attn_out[(mbase + qq) * 200 + h * 25 + p] = a;
        int pi = p / 5, pj = p - pi * 5;
        float g0 = (float)(pj - 2) * 0.2f * prm[qq][2];
        float g1 = (float)(pi - 2) * 0.2f * prm[qq][3];
        float ca = prm[qq][4], sa = prm[qq][5];
        float gx = (prm[qq][0] + g0 * ca - g1 * sa) * (float)Wf - 0.5f;
        float gy = (prm[qq][1] + g0 * sa + g1 * ca) * (float)Hf - 0.5f;
        float x0f = floorf(gx), y0f = floorf(gy);
        int x0 = (int)x0f, y0 = (int)y0f;
        float wx1 = gx - x0f, wy1 = gy - y0f;
        float wx0 = 1.f - wx1, wy0 = 1.f - wy1;
        int y1 = y0 + 1;
        int bx; float wl, wr;
        if (x0 >= 0 && x0 <= Wf - 2)      { bx = x0;     wl = wx0; wr = wx1; }
        else if (x0 == -1)                { bx = 0;      wl = wx1; wr = 0.f; }
        else if (x0 == Wf - 1)            { bx = Wf - 2; wl = 0.f; wr = wx0; }
        else                              { bx = 0;      wl = 0.f; wr = 0.f; }
        float wy0v = (y0 >= 0 && y0 < Hf) ? wy0 : 0.f;
        float wy1v = (y1 >= 0 && y1 < Hf) ? wy1 : 0.f;
        int cy0 = min(max(y0, 0), Hf - 1), cy1 = min(max(y1, 0), Hf - 1);
        unsigned off0 = (unsigned)(cy0 * Wf + bx) * 16u;
        unsigned off1 = (unsigned)(cy1 * Wf + bx) * 16u;
        float aw0 = a * wy0v, aw1 = a * wy1v;
        pk[qq][p][0] = make_uint4(__float_as_uint(aw0 * wl), __float_as_uint(aw1 * wl), off0, off1);
        pk[qq][p][1] = make_uint4(__float_as_uint(aw0 * wr), __float_as_uint(aw1 * wr), off0, off1);
    }
    __syncthreads();

    const int qq = tid >> 5, l = tid & 31;
    const unsigned int* vw = (const unsigned int*)(v + (size_t)s * LV * 32);
    const uint4* pkp = &pk[qq][0][l >> 4];
    float e0 = 0.f, o0 = 0.f, e1 = 0.f, o1 = 0.f;
#pragma unroll
    for (int p = 0; p < 25; ++p) {
        uint4 t = pkp[2 * p];                 // ds_read_b128
        float w0 = __uint_as_float(t.x), w1 = __uint_as_float(t.y);
        unsigned u0 = vw[t.z + l];
        unsigned u1 = vw[t.w + l];
        e0 += w0 * __uint_as_float(u0 << 16);
        o0 += w0 * __uint_as_float(u0 & 0xffff0000u);
        e1 += w1 * __uint_as_float(u1 << 16);
        o1 += w1 * __uint_as_float(u1 & 0xffff0000u);
    }
    float a0 = e0 + e1, a1 = o0 + o1;
    a0 += __shfl_xor(a0, 16, 32);
    a1 += __shfl_xor(a1, 16, 32);
    if (l < 16)
        ((unsigned int*)ohbf)[(mbase + qq) * 128 + h * 16 + l] = pack2(a0, a1);
}

extern "C" void kernel_launch(void* const* d_in, const int* in_sizes, int n_in,
                              void* d_out, int out_size, void* d_ws, size_t ws_size,
                              hipStream_t stream) {
    const float* query       = (const float*)d_in[0];
    const float* value       = (const float*)d_in[1];
    const float* ref_windows = (const float*)d_in[2];
    const float* W_box       = (const float*)d_in[3];
    const float* b_box       = (const float*)d_in[4];
    const float* W_attn      = (const float*)d_in[5];
    const float* b_attn      = (const float*)d_in[6];
    const float* W_value     = (const float*)d_in[7];
    const float* b_value     = (const float*)d_in[8];
    const float* W_out       = (const float*)d_in[9];
    const float* b_out       = (const float*)d_in[10];
    const int*   Hf          = (const int*)d_in[11];
    const int*   Wf          = (const int*)d_in[12];

    const int M1 = in_sizes[1] / 256;  // B*LV = 70688
    const int MQ = in_sizes[0] / 256;  // B*LQ = 8192
    const int LQ = MQ / 2;
    const int LV = M1 / 2;

    unsigned short* vbf  = (unsigned short*)d_ws;                 // M1*256
    unsigned short* Vout = vbf + (size_t)M1 * 256;                // M1*256
    unsigned short* ohbf = Vout + (size_t)M1 * 256;               // MQ*256
    unsigned short* wvbf = ohbf + (size_t)MQ * 256;               // 65536
    unsigned short* wabf = wvbf + 65536;                          // 65536
    unsigned short* wobf = wabf + 65536;                          // 65536
    float* Wab       = (float*)(wobf + 65536);                    // 65536 fp32
    float* bab       = Wab + 65536;                               // 256
    float* logits    = bab + 256;                                 // MQ*256

    float* out0     = (float*)d_out;
    float* attn_out = out0 + (size_t)MQ * 256;

    const long long nv4 = (long long)M1 * 64;

    // K0: conversions (2048 + 16 + 16 + 16 + 1 = 2097 blocks)
    convert_kernel<<<2097, 256, 0, stream>>>(value, vbf, nv4, W_value, wvbf,
                                             W_attn, W_box, wabf, Wab,
                                             W_out, wobf, b_attn, b_box, bab);
    // K1: value projection -> head-major bf16 Vout
    dim3 g1((M1 + 127) / 128, 2);
    gemm_bf16<1><<<g1, 256, 0, stream>>>(vbf, wvbf, b_value, Vout, M1, LV);
    // K2: logits fp32 (accuracy-critical box path)
    dim3 g2(MQ / 64, 4);
    gemm_nt_bias<<<g2, 256, 0, stream>>>(query, Wab, bab, logits, MQ);
    // K3: XCD-affine fused softmax + box decode + gather -> bf16 out_heads
    decode_sample_kernel<<<dim3(16, LQ / 8), 256, 0, stream>>>(
        Vout, logits, ref_windows, attn_out, ohbf, Hf, Wf, LV, LQ);
    // K4: output projection via bf16 MFMA
    dim3 g4(MQ / 128, 2);
    gemm_bf16<0><<<g4, 256, 0, stream>>>(ohbf, wobf, b_out, out0, MQ, LV);
}